// Round 13
// baseline (181.128 us; speedup 1.0000x reference)
//
#include <hip/hip_runtime.h>
#include <hip/hip_bf16.h>

// GAT layer: h = doc@W + Wb; s1 = h@a1, s2 = h@a2;
// score[i,j] = lrelu(s1[i]+s2[j]+ab); att = softmax_rows(score); out = lrelu(att@h)
// N=8192, IN=512, D=256. Outputs: out (8192*256) then att (8192*8192), fp32.
//
// w_ij = (e2_j >= T_i) ? E1_i*e2_j : E01_i*e02_j  with e2=exp(s2), e02=exp(.1*s2),
// T_i = exp(-s1a_i). Condition is a THRESHOLD on e2_j -> sort j by e2 descending:
// {j : e2_j >= T_i} = first c_i sorted elements. Then
//   out[i,:] = E1z_i * P1[c_i-1,:] + E01z_i * (P2tot - P2[c_i-1,:])
// with P1/P2 prefix sums of e2srt*h / e02srt*h (fp64-accumulated). No MFMA for out,
// no Z-loop: Z from scalar prefix sums + binary search. att = pure streaming writes.

typedef __attribute__((ext_vector_type(4))) float f32x4;
typedef __attribute__((ext_vector_type(8))) short short8;

#define SLOPE 0.1f
#define NROW 8192
#define DDIM 256

__device__ __forceinline__ float lrelu(float x){ return fmaxf(x, SLOPE * x); }

__device__ __forceinline__ unsigned short f2bf(float f){
  union { float f; unsigned u; } v; v.f = f;
  unsigned r = (v.u + 0x7fffu + ((v.u >> 16) & 1u)) >> 16;
  return (unsigned short)r;
}
__device__ __forceinline__ float bf2f(unsigned short u){
  union { unsigned u; float f; } v; v.u = (unsigned)u << 16; return v.f;
}

// ---------------- K0: Wt_hi/Wt_lo [256][512] bf16 split-transpose of W ----------------
__global__ __launch_bounds__(256) void k_prep(
    const float* __restrict__ W,
    unsigned short* __restrict__ Wt_hi, unsigned short* __restrict__ Wt_lo)
{
  typedef __attribute__((ext_vector_type(4))) unsigned short ushort4v;
  const int tid = blockIdx.x * 256 + threadIdx.x;   // 32768 total
  const int c = tid >> 7, kq = tid & 127;
  ushort4v hi, lo;
#pragma unroll
  for (int j = 0; j < 4; ++j) {
    const float v = W[(size_t)(kq * 4 + j) * 256 + c];
    hi[j] = f2bf(v);
    lo[j] = f2bf(v - bf2f(hi[j]));
  }
  *reinterpret_cast<ushort4v*>(Wt_hi + (size_t)c * 512 + kq * 4) = hi;
  *reinterpret_cast<ushort4v*>(Wt_lo + (size_t)c * 512 + kq * 4) = lo;
}

// ---------------- K1: h (fp32) via split MFMA; fused s1/e2/e02 ----------------
// 512 threads = 8 waves. Block = 32 rows x 256 cols; wave w owns cols w*32..+31.
__global__ __launch_bounds__(512, 2) void k_h(
    const float* __restrict__ doc, const unsigned short* __restrict__ Wt_hi,
    const unsigned short* __restrict__ Wt_lo, const float* __restrict__ Wb,
    const float* __restrict__ a,
    float* __restrict__ h, float* __restrict__ s1,
    float* __restrict__ e2, float* __restrict__ e02)
{
  __shared__ __align__(16) short8 aH[2][2][64];
  __shared__ __align__(16) short8 aL[2][2][64];
  __shared__ float sred[8][2][32];

  const int t = threadIdx.x, w = t >> 6, l = t & 63;
  const int lr = l & 15, lg = l >> 4;
  const int rb = blockIdx.x * 32;
  const int cb = w * 32;

  f32x4 acc[2][2];
#pragma unroll
  for (int rt = 0; rt < 2; ++rt)
#pragma unroll
    for (int ct = 0; ct < 2; ++ct) acc[rt][ct] = (f32x4){0.f, 0.f, 0.f, 0.f};

  const float* docp = doc + (size_t)(rb + w * 16 + lr) * 512 + lg * 8;  // valid for w<2

  f32x4 v0, v1;
  auto loadDoc = [&](int k0) { if (w < 2) {
      v0 = *reinterpret_cast<const f32x4*>(docp + k0);
      v1 = *reinterpret_cast<const f32x4*>(docp + k0 + 4);
  }};
  auto writeStage = [&](int pb) { if (w < 2) {
      union { short8 v; unsigned short u[8]; } hi, lo;
#pragma unroll
      for (int q = 0; q < 4; ++q) {
        hi.u[q] = f2bf(v0[q]);     lo.u[q] = f2bf(v0[q] - bf2f(hi.u[q]));
        hi.u[4+q] = f2bf(v1[q]);   lo.u[4+q] = f2bf(v1[q] - bf2f(hi.u[4+q]));
      }
      aH[pb][w][l] = hi.v;
      aL[pb][w][l] = lo.v;
  }};

  loadDoc(0); writeStage(0); loadDoc(32);

  for (int n = 0; n < 16; ++n) {
    const int kk = n * 32;
    const int par = n & 1;

    asm volatile("s_waitcnt lgkmcnt(0)\n\ts_barrier" ::: "memory");

    const short8 ah0 = aH[par][0][l];
    const short8 ah1 = aH[par][1][l];
    const short8 al0 = aL[par][0][l];
    const short8 al1 = aL[par][1][l];

    short8 bh[2], bl[2];
#pragma unroll
    for (int ct = 0; ct < 2; ++ct) {
      const size_t off = (size_t)(cb + ct * 16 + lr) * 512 + kk + lg * 8;
      bh[ct] = *reinterpret_cast<const short8*>(Wt_hi + off);
      bl[ct] = *reinterpret_cast<const short8*>(Wt_lo + off);
    }

    if (n + 1 < 16) writeStage(par ^ 1);
    if (n + 2 < 16) loadDoc((n + 2) * 32);

#pragma unroll
    for (int ct = 0; ct < 2; ++ct) {
      acc[0][ct] = __builtin_amdgcn_mfma_f32_16x16x32_bf16(ah0, bh[ct], acc[0][ct], 0, 0, 0);
      acc[1][ct] = __builtin_amdgcn_mfma_f32_16x16x32_bf16(ah1, bh[ct], acc[1][ct], 0, 0, 0);
      acc[0][ct] = __builtin_amdgcn_mfma_f32_16x16x32_bf16(ah0, bl[ct], acc[0][ct], 0, 0, 0);
      acc[1][ct] = __builtin_amdgcn_mfma_f32_16x16x32_bf16(ah1, bl[ct], acc[1][ct], 0, 0, 0);
      acc[0][ct] = __builtin_amdgcn_mfma_f32_16x16x32_bf16(al0, bh[ct], acc[0][ct], 0, 0, 0);
      acc[1][ct] = __builtin_amdgcn_mfma_f32_16x16x32_bf16(al1, bh[ct], acc[1][ct], 0, 0, 0);
    }
  }

  float bias[2];
#pragma unroll
  for (int ct = 0; ct < 2; ++ct) bias[ct] = Wb[cb + ct * 16 + lr];
#pragma unroll
  for (int rt = 0; rt < 2; ++rt)
#pragma unroll
    for (int ct = 0; ct < 2; ++ct)
#pragma unroll
      for (int q = 0; q < 4; ++q) {
        acc[rt][ct][q] += bias[ct];
        h[(size_t)(rb + rt * 16 + lg * 4 + q) * 256 + cb + ct * 16 + lr] = acc[rt][ct][q];
      }

  // s1/s2 over this wave's 32 cols; reduce over lr then waves
  float a1c[2], a2c[2];
#pragma unroll
  for (int ct = 0; ct < 2; ++ct) {
    a1c[ct] = a[cb + ct * 16 + lr];
    a2c[ct] = a[256 + cb + ct * 16 + lr];
  }
  float p1[2][4], p2[2][4];
#pragma unroll
  for (int rt = 0; rt < 2; ++rt)
#pragma unroll
    for (int q = 0; q < 4; ++q) {
      float x1 = 0.f, x2 = 0.f;
#pragma unroll
      for (int ct = 0; ct < 2; ++ct) {
        x1 = fmaf(acc[rt][ct][q], a1c[ct], x1);
        x2 = fmaf(acc[rt][ct][q], a2c[ct], x2);
      }
#pragma unroll
      for (int off = 1; off < 16; off <<= 1) {
        x1 += __shfl_xor(x1, off);
        x2 += __shfl_xor(x2, off);
      }
      p1[rt][q] = x1; p2[rt][q] = x2;
    }
  __syncthreads();
  if (lr == 0) {
#pragma unroll
    for (int rt = 0; rt < 2; ++rt)
#pragma unroll
      for (int q = 0; q < 4; ++q) {
        sred[w][0][rt * 16 + lg * 4 + q] = p1[rt][q];
        sred[w][1][rt * 16 + lg * 4 + q] = p2[rt][q];
      }
  }
  __syncthreads();
  if (t < 32) {
    float v1s = 0.f, v2s = 0.f;
#pragma unroll
    for (int ww = 0; ww < 8; ++ww) { v1s += sred[ww][0][t]; v2s += sred[ww][1][t]; }
    const int r = rb + t;
    s1[r] = v1s;
    e2[r] = __expf(v2s);
    e02[r] = __expf(SLOPE * v2s);
  }
}

// ---------------- K2: sort j by e2 descending (rank-count + scatter) ----------------
// grid 256 x 256 threads; 8 threads per j (each scans 1024 of 8192), shfl-reduce.
__global__ __launch_bounds__(256) void k_sort(
    const float* __restrict__ e2, const float* __restrict__ e02,
    int* __restrict__ sortIdx, float* __restrict__ e2srt, float* __restrict__ e02srt)
{
  __shared__ __align__(16) float e2L[8192];
  const int t = threadIdx.x;
  for (int i = t * 4; i < 8192; i += 1024)
    *reinterpret_cast<f32x4*>(&e2L[i]) = *reinterpret_cast<const f32x4*>(e2 + i);
  __syncthreads();
  const int j = blockIdx.x * 32 + (t >> 3);
  const int sub = t & 7;
  const float v = e2L[j];
  const int k0 = sub * 1024;
  int cnt = 0;
  for (int ii = 0; ii < 1024; ii += 4) {
    const int i = (ii + sub * 132) & 1023;   // stagger: spread banks across subs
    const f32x4 x = *reinterpret_cast<const f32x4*>(&e2L[k0 + i]);
#pragma unroll
    for (int q = 0; q < 4; ++q) {
      const int k = k0 + i + q;
      cnt += (x[q] > v || (x[q] == v && k < j)) ? 1 : 0;
    }
  }
  cnt += __shfl_down(cnt, 4);
  cnt += __shfl_down(cnt, 2);
  cnt += __shfl_down(cnt, 1);
  if (sub == 0) {
    sortIdx[cnt] = j;
    e2srt[cnt] = v;
    e02srt[cnt] = e02[j];
  }
}

// ---------------- K3: scalar prefix sums of e2srt / e02srt (fp64 internal) ----------------
__global__ __launch_bounds__(256) void k_scan(
    const float* __restrict__ e2srt, const float* __restrict__ e02srt,
    float* __restrict__ pe2, float* __restrict__ pe02)
{
  __shared__ double psum[256];
  const int t = threadIdx.x;
  for (int pass = 0; pass < 2; ++pass) {
    const float* src = pass ? e02srt : e2srt;
    float* dst = pass ? pe02 : pe2;
    double s = 0;
    for (int r = t * 32; r < t * 32 + 32; ++r) s += (double)src[r];
    psum[t] = s;
    __syncthreads();
    if (t == 0) {
      double acc = 0;
      for (int i = 0; i < 256; ++i) { double tmp = psum[i]; psum[i] = acc; acc += tmp; }
    }
    __syncthreads();
    double acc = psum[t];
    for (int r = t * 32; r < t * 32 + 32; ++r) { acc += (double)src[r]; dst[r] = (float)acc; }
    __syncthreads();
  }
}

// ---------------- K4: per-row c_i, rowinfo {E1z, E01z, T, iz} ----------------
__global__ __launch_bounds__(256) void k_rowinfo(
    const float* __restrict__ s1, const float* __restrict__ abp,
    const float* __restrict__ e2srt, const float* __restrict__ pe2,
    const float* __restrict__ pe02,
    float* __restrict__ rowinfo, int* __restrict__ cArr)
{
  const int i = blockIdx.x * 256 + threadIdx.x;
  const float s1a = s1[i] + abp[0];
  const float E1 = __expf(s1a), E01 = __expf(SLOPE * s1a), T = __expf(-s1a);
  // count of e2srt[r] >= T (descending order)
  int lo = 0, hi = 8192;
  while (lo < hi) {
    const int m = (lo + hi) >> 1;
    if (e2srt[m] >= T) lo = m + 1; else hi = m;
  }
  const int c = lo;
  const float pe02tot = pe02[8191];
  const float sum1 = (c > 0) ? pe2[c - 1] : 0.f;
  const float sum2 = pe02tot - ((c > 0) ? pe02[c - 1] : 0.f);
  const float Z = E1 * sum1 + E01 * sum2;
  const float iz = 1.0f / Z;
  f32x4 ri = (f32x4){E1 * iz, E01 * iz, T, iz};
  *reinterpret_cast<f32x4*>(rowinfo + (size_t)i * 4) = ri;
  cArr[i] = c;
}

// ---------------- K5: per-segment sums of e2srt*h, e02srt*h (64 segs x 128) ----------------
__global__ __launch_bounds__(256) void k_segsum(
    const int* __restrict__ sortIdx, const float* __restrict__ e2srt,
    const float* __restrict__ e02srt, const float* __restrict__ h,
    float* __restrict__ seg1, float* __restrict__ seg2)
{
  const int s = blockIdx.x, d = threadIdx.x;
  double a1 = 0, a2 = 0;
  for (int r = s * 128; r < s * 128 + 128; ++r) {
    const int j = sortIdx[r];
    const float hv = h[(size_t)j * 256 + d];
    a1 += (double)e2srt[r] * hv;
    a2 += (double)e02srt[r] * hv;
  }
  seg1[(size_t)s * 256 + d] = (float)a1;
  seg2[(size_t)s * 256 + d] = (float)a2;
}

// ---------------- K6: inclusive vector prefix sums P1, P2 ----------------
__global__ __launch_bounds__(256) void k_prefix(
    const int* __restrict__ sortIdx, const float* __restrict__ e2srt,
    const float* __restrict__ e02srt, const float* __restrict__ h,
    const float* __restrict__ seg1, const float* __restrict__ seg2,
    float* __restrict__ P1, float* __restrict__ P2)
{
  const int s = blockIdx.x, d = threadIdx.x;
  double a1 = 0, a2 = 0;
  for (int s2 = 0; s2 < s; ++s2) {
    a1 += (double)seg1[(size_t)s2 * 256 + d];
    a2 += (double)seg2[(size_t)s2 * 256 + d];
  }
  for (int r = s * 128; r < s * 128 + 128; ++r) {
    const int j = sortIdx[r];
    const float hv = h[(size_t)j * 256 + d];
    a1 += (double)e2srt[r] * hv;
    a2 += (double)e02srt[r] * hv;
    P1[(size_t)r * 256 + d] = (float)a1;
    P2[(size_t)r * 256 + d] = (float)a2;
  }
}

// ---------------- K7: att streaming writer (no MFMA, no barriers in loop) ----------------
// grid (4, 512): bx = 2048-col slice, by = 16-row block. 256 threads = 4 waves,
// wave w rows w*4..+3; per row 8 consecutive 1-KB store instrs (8 KB burst/row).
__global__ __launch_bounds__(256) void k_att(
    const float* __restrict__ rowinfo, const float* __restrict__ e2g,
    const float* __restrict__ e02g, float* __restrict__ att)
{
  __shared__ __align__(16) float e2s[2048];
  __shared__ __align__(16) float f2s[2048];
  __shared__ __align__(16) f32x4 rin[16];
  const int t = threadIdx.x, w = t >> 6, l = t & 63;
  const int kbase = blockIdx.x * 2048;
  const int rb = blockIdx.y * 16;
  for (int i = t * 4; i < 2048; i += 1024) {
    *reinterpret_cast<f32x4*>(&e2s[i]) = *reinterpret_cast<const f32x4*>(e2g + kbase + i);
    *reinterpret_cast<f32x4*>(&f2s[i]) = *reinterpret_cast<const f32x4*>(e02g + kbase + i);
  }
  if (t < 16) rin[t] = *reinterpret_cast<const f32x4*>(rowinfo + (size_t)(rb + t) * 4);
  __syncthreads();
#pragma unroll
  for (int rr = 0; rr < 4; ++rr) {
    const int row = rb + w * 4 + rr;
    const f32x4 ri = rin[w * 4 + rr];
    const float E1z = ri[0], E01z = ri[1], T = ri[2];
    float* ap = att + (size_t)row * 8192 + kbase + l * 4;
#pragma unroll
    for (int c = 0; c < 8; ++c) {
      const int jo = c * 256 + l * 4;
      const f32x4 e = *reinterpret_cast<const f32x4*>(&e2s[jo]);
      const f32x4 f = *reinterpret_cast<const f32x4*>(&f2s[jo]);
      f32x4 p;
#pragma unroll
      for (int q = 0; q < 4; ++q) {
        const bool cc = (e[q] >= T);
        p[q] = (cc ? E1z : E01z) * (cc ? e[q] : f[q]);
      }
      *reinterpret_cast<f32x4*>(ap + c * 256) = p;   // plain store (fill-like streaming)
    }
  }
}

// ---------------- K8: out[i,:] = lrelu(E1z*P1[c-1] + E01z*(P2tot - P2[c-1])) ----------------
__global__ __launch_bounds__(256) void k_out(
    const float* __restrict__ rowinfo, const int* __restrict__ cArr,
    const float* __restrict__ P1, const float* __restrict__ P2,
    float* __restrict__ out)
{
  __shared__ float eL[16], fL[16];
  __shared__ int cL[16];
  const int t = threadIdx.x;
  const int rb = blockIdx.x * 16;
  if (t < 16) {
    const f32x4 ri = *reinterpret_cast<const f32x4*>(rowinfo + (size_t)(rb + t) * 4);
    eL[t] = ri[0]; fL[t] = ri[1]; cL[t] = cArr[rb + t];
  }
  __syncthreads();
  const float tot2 = P2[(size_t)8191 * 256 + t];
#pragma unroll 4
  for (int rr = 0; rr < 16; ++rr) {
    const int c = cL[rr];
    const float p1 = (c > 0) ? P1[(size_t)(c - 1) * 256 + t] : 0.f;
    const float p2 = tot2 - ((c > 0) ? P2[(size_t)(c - 1) * 256 + t] : 0.f);
    out[(size_t)(rb + rr) * 256 + t] = lrelu(eL[rr] * p1 + fL[rr] * p2);
  }
}

extern "C" void kernel_launch(void* const* d_in, const int* in_sizes, int n_in,
                              void* d_out, int out_size, void* d_ws, size_t ws_size,
                              hipStream_t stream)
{
  const float* doc = (const float*)d_in[0];
  const float* W   = (const float*)d_in[1];
  const float* Wb  = (const float*)d_in[2];
  const float* a   = (const float*)d_in[3];
  const float* ab  = (const float*)d_in[4];

  float* out = (float*)d_out;                 // 8192*256
  float* att = out + (size_t)8192 * 256;      // 8192*8192

  char* ws = (char*)d_ws;
  float* h              = (float*)ws;                                       // 8 MB
  unsigned short* Wt_hi = (unsigned short*)(ws + (size_t)8  * 1024 * 1024); // 256 KB
  unsigned short* Wt_lo = (unsigned short*)(ws + (size_t)8  * 1024 * 1024 + 262144);
  char* tb = ws + (size_t)8 * 1024 * 1024 + 524288;
  float* s1      = (float*)(tb);               // 32 KB each below
  float* e2      = s1 + 8192;
  float* e02     = e2 + 8192;
  float* e2srt   = e02 + 8192;
  float* e02srt  = e2srt + 8192;
  float* pe2     = e02srt + 8192;
  float* pe02    = pe2 + 8192;
  int*   sortIdx = (int*)(pe02 + 8192);
  int*   cArr    = sortIdx + 8192;
  float* rowinfo = (float*)(cArr + 8192);      // 128 KB
  float* seg1    = rowinfo + 8192 * 4;         // 64 KB
  float* seg2    = seg1 + 64 * 256;            // 64 KB
  float* P1      = (float*)(ws + (size_t)16 * 1024 * 1024);  // 8 MB
  float* P2      = (float*)(ws + (size_t)24 * 1024 * 1024);  // 8 MB

  hipLaunchKernelGGL(k_prep,    dim3(128),      dim3(256), 0, stream, W, Wt_hi, Wt_lo);
  hipLaunchKernelGGL(k_h,       dim3(256),      dim3(512), 0, stream, doc, Wt_hi, Wt_lo, Wb, a, h, s1, e2, e02);
  hipLaunchKernelGGL(k_sort,    dim3(256),      dim3(256), 0, stream, e2, e02, sortIdx, e2srt, e02srt);
  hipLaunchKernelGGL(k_scan,    dim3(1),        dim3(256), 0, stream, e2srt, e02srt, pe2, pe02);
  hipLaunchKernelGGL(k_rowinfo, dim3(32),       dim3(256), 0, stream, s1, ab, e2srt, pe2, pe02, rowinfo, cArr);
  hipLaunchKernelGGL(k_segsum,  dim3(64),       dim3(256), 0, stream, sortIdx, e2srt, e02srt, h, seg1, seg2);
  hipLaunchKernelGGL(k_prefix,  dim3(64),       dim3(256), 0, stream, sortIdx, e2srt, e02srt, h, seg1, seg2, P1, P2);
  hipLaunchKernelGGL(k_att,     dim3(4, 512),   dim3(256), 0, stream, rowinfo, e2, e02, att);
  hipLaunchKernelGGL(k_out,     dim3(512),      dim3(256), 0, stream, rowinfo, cArr, P1, P2, out);
}